// Round 1
// 3228.908 us; speedup vs baseline: 1.7462x; 1.7462x over previous
//
#include <hip/hip_runtime.h>
#include <cstddef>
#include <cstdint>

#define N_ROWS 65536
#define DIM    256
#define NE     8192

// output layout (float elements): x_q_ste[16777216] | loss[1] | indices[65536] | d[536870912]
#define OUT_LOSS ((size_t)16777216)
#define OUT_IDX  ((size_t)16777217)
#define OUT_D    ((size_t)16842753)

typedef _Float16 f16;
typedef __attribute__((ext_vector_type(8))) _Float16 f16x8;
typedef __attribute__((ext_vector_type(4))) _Float16 f16x4;
typedef __attribute__((ext_vector_type(4))) float f32x4;

// async global->LDS, 16B/lane; LDS dest = wave-uniform base + lane*16
__device__ __forceinline__ void gl_lds16(const void* g, void* lds_base) {
  __builtin_amdgcn_global_load_lds(
      (const __attribute__((address_space(1))) void*)g,
      (__attribute__((address_space(3))) void*)(uint32_t)(uintptr_t)lds_base,
      16, 0, 0);
}

// ---------------------------------------------------------------------------
// prep: split x into fp16 hi/lo (scaled by 2^4) and compute per-row sum(x^2).
// one wave per row; float4 load = 16B/lane.
__global__ __launch_bounds__(256) void prep_x(const float* __restrict__ x,
                                              f16* __restrict__ xh,
                                              f16* __restrict__ xl,
                                              float* __restrict__ c_g) {
  const int wave = threadIdx.x >> 6, lane = threadIdx.x & 63;
  const int row = blockIdx.x * 4 + wave;
  const float4 v = *(const float4*)(x + (size_t)row * DIM + 4 * lane);
  float s = v.x * v.x + v.y * v.y + v.z * v.z + v.w * v.w;
  const float a0 = v.x * 16.f, a1 = v.y * 16.f, a2 = v.z * 16.f, a3 = v.w * 16.f;
  f16x4 h, lo;
  h[0] = (f16)a0; lo[0] = (f16)(a0 - (float)h[0]);
  h[1] = (f16)a1; lo[1] = (f16)(a1 - (float)h[1]);
  h[2] = (f16)a2; lo[2] = (f16)(a2 - (float)h[2]);
  h[3] = (f16)a3; lo[3] = (f16)(a3 - (float)h[3]);
  *(f16x4*)(xh + (size_t)row * DIM + 4 * lane) = h;
  *(f16x4*)(xl + (size_t)row * DIM + 4 * lane) = lo;
  #pragma unroll
  for (int off = 32; off; off >>= 1) s += __shfl_down(s, off);
  if (lane == 0) c_g[row] = s;
}

// prep: split emb into fp16 hi/lo (scaled by 2^16 so the lo part stays in
// fp16 normal range) and compute per-code sum(e^2) (unscaled).
__global__ __launch_bounds__(256) void prep_e(const float* __restrict__ e,
                                              f16* __restrict__ eh,
                                              f16* __restrict__ el,
                                              float* __restrict__ e2_g) {
  const int wave = threadIdx.x >> 6, lane = threadIdx.x & 63;
  const int row = blockIdx.x * 4 + wave;
  const float4 v = *(const float4*)(e + (size_t)row * DIM + 4 * lane);
  float s = v.x * v.x + v.y * v.y + v.z * v.z + v.w * v.w;
  const float a0 = v.x * 65536.f, a1 = v.y * 65536.f, a2 = v.z * 65536.f, a3 = v.w * 65536.f;
  f16x4 h, lo;
  h[0] = (f16)a0; lo[0] = (f16)(a0 - (float)h[0]);
  h[1] = (f16)a1; lo[1] = (f16)(a1 - (float)h[1]);
  h[2] = (f16)a2; lo[2] = (f16)(a2 - (float)h[2]);
  h[3] = (f16)a3; lo[3] = (f16)(a3 - (float)h[3]);
  *(f16x4*)(eh + (size_t)row * DIM + 4 * lane) = h;
  *(f16x4*)(el + (size_t)row * DIM + 4 * lane) = lo;
  #pragma unroll
  for (int off = 32; off; off >>= 1) s += __shfl_down(s, off);
  if (lane == 0) e2_g[row] = s;
}

// ---------------------------------------------------------------------------
// main kernel: 128x128 tile, BK=32, m97-style structure.
// dot = xh*eh + xh*el + xl*eh  (fp16 MFMA, fp32 accumulate); net scale 2^20.
// d = fl( fl(c + e2) - fl(2*dot) )  with 2*dot = acc * 2^-19 (exact scaling).
__global__ __launch_bounds__(256) void vq_mfma(
    const f16* __restrict__ xh, const f16* __restrict__ xl,
    const f16* __restrict__ eh, const f16* __restrict__ el,
    const float* __restrict__ c_g, const float* __restrict__ e2_g,
    float* __restrict__ dD, unsigned long long* __restrict__ minkey) {
  __shared__ f16 As[128 * 32];   // [row][k], 64B/row, linear (global_load_lds)
  __shared__ f16 Bs[128 * 32];   // [code][k]

  const int t = threadIdx.x;
  const int w = t >> 6, l = t & 63;
  const int g = l >> 4, rr = l & 15;
  const int wr = w >> 1, wc = w & 1;     // 2x2 waves, each owns 64x64 output
  const int col0 = blockIdx.x * 128, row0 = blockIdx.y * 128;

  f32x4 acc[4][4];
  #pragma unroll
  for (int m = 0; m < 4; m++)
    #pragma unroll
    for (int n = 0; n < 4; n++) acc[m][n] = (f32x4){0.f, 0.f, 0.f, 0.f};

  const int f0 = w * 2 * 64 + l;  // staging flat index; instr i adds 64

  #pragma unroll 1
  for (int p = 0; p < 3; ++p) {
    // pass order: small terms first. p0: xh*el, p1: xl*eh, p2: xh*eh
    const f16* Ag = ((p == 1) ? xl : xh) + (size_t)row0 * DIM;
    const f16* Bg = ((p == 0) ? el : eh) + (size_t)col0 * DIM;
    for (int k0 = 0; k0 < DIM; k0 += 32) {
      __syncthreads();  // protect previous tile's reads
      #pragma unroll
      for (int i = 0; i < 2; ++i) {
        const int f = f0 + i * 64;
        const int r = f >> 2, kc = f & 3;      // 4 x 16B chunks per 64B row
        const size_t goff = (size_t)r * DIM + k0 + 8 * kc;
        gl_lds16(Ag + goff, (char*)As + (size_t)(w * 2 + i) * 1024);
        gl_lds16(Bg + goff, (char*)Bs + (size_t)(w * 2 + i) * 1024);
      }
      __syncthreads();  // vmcnt(0) drain: tiles resident
      f16x8 af[4], bf[4];
      #pragma unroll
      for (int m = 0; m < 4; m++)
        af[m] = *(const f16x8*)(As + (wr * 64 + m * 16 + rr) * 32 + g * 8);
      #pragma unroll
      for (int n = 0; n < 4; n++)
        bf[n] = *(const f16x8*)(Bs + (wc * 64 + n * 16 + rr) * 32 + g * 8);
      #pragma unroll
      for (int m = 0; m < 4; m++)
        #pragma unroll
        for (int n = 0; n < 4; n++)
          acc[m][n] = __builtin_amdgcn_mfma_f32_16x16x32_f16(af[m], bf[n], acc[m][n], 0, 0, 0);
    }
  }

  // epilogue: d values + stores + per-row argmin (ref tie-break: lowest index)
  float e2c[4];
  int Cc[4];
  #pragma unroll
  for (int n = 0; n < 4; n++) {
    Cc[n] = col0 + wc * 64 + n * 16 + rr;
    e2c[n] = e2_g[Cc[n]];
  }
  const float kscale = 1.9073486328125e-6f;  // 2^-19, exact

  #pragma unroll
  for (int m = 0; m < 4; m++) {
    #pragma unroll
    for (int q = 0; q < 4; q++) {  // C/D: col = lane&15, row = (lane>>4)*4 + q
      const int R = row0 + wr * 64 + m * 16 + g * 4 + q;
      const float cr = c_g[R];
      float bv = 3.4e38f;
      int bc = 0;
      float vals[4];
      #pragma unroll
      for (int n = 0; n < 4; n++) {
        const float t1 = cr + e2c[n];
        const float v = t1 - acc[m][n][q] * kscale;
        vals[n] = v;
        if (v < bv) { bv = v; bc = Cc[n]; }  // n ascending => smallest col on ties
      }
      float* drow = dD + (size_t)R * NE;
      #pragma unroll
      for (int n = 0; n < 4; n++)
        __builtin_nontemporal_store(vals[n], drow + Cc[n]);

      unsigned int fb = __float_as_uint(bv);
      fb = (fb & 0x80000000u) ? ~fb : (fb | 0x80000000u);
      unsigned long long key = ((unsigned long long)fb << 32) | (unsigned int)bc;
      #pragma unroll
      for (int off = 8; off; off >>= 1) {
        unsigned long long o = __shfl_down(key, off, 16);
        if (o < key) key = o;
      }
      if (rr == 0) atomicMin(&minkey[R], key);
    }
  }
}

// ---------------------------------------------------------------------------
// epilogue: x_q_ste = fl(x + fl(x_q - x)), indices (as float), loss partials
__global__ __launch_bounds__(256) void vq_epilogue(
    const float* __restrict__ x, const float* __restrict__ emb,
    const unsigned long long* __restrict__ minkey,
    float* __restrict__ out, float* __restrict__ blocksum) {
  __shared__ float wsum[4];
  const int wave = threadIdx.x >> 6, lane = threadIdx.x & 63;
  const int row = blockIdx.x * 4 + wave;
  const unsigned long long key = minkey[row];
  const int idx = (int)(unsigned int)(key & 0xFFFFFFFFULL);

  const float4 xv = *(const float4*)(x + (size_t)row * DIM + 4 * lane);
  const float4 ev = *(const float4*)(emb + (size_t)idx * DIM + 4 * lane);
  const float d0 = ev.x - xv.x, d1 = ev.y - xv.y, d2 = ev.z - xv.z, d3 = ev.w - xv.w;
  float4 o;
  o.x = xv.x + d0; o.y = xv.y + d1; o.z = xv.z + d2; o.w = xv.w + d3;
  *(float4*)(out + (size_t)row * DIM + 4 * lane) = o;

  float s = d0 * d0 + d1 * d1 + d2 * d2 + d3 * d3;
  #pragma unroll
  for (int off = 32; off; off >>= 1) s += __shfl_down(s, off);
  if (lane == 0) {
    wsum[wave] = s;
    out[OUT_IDX + row] = (float)idx;
  }
  __syncthreads();
  if (threadIdx.x == 0) blocksum[blockIdx.x] = wsum[0] + wsum[1] + wsum[2] + wsum[3];
}

__global__ void vq_finalize(const float* __restrict__ bs, float* __restrict__ out) {
  __shared__ float red[4];
  float s = 0.f;
  for (int i = threadIdx.x; i < N_ROWS / 4; i += 256) s += bs[i];
  #pragma unroll
  for (int off = 32; off; off >>= 1) s += __shfl_down(s, off);
  const int wave = threadIdx.x >> 6, lane = threadIdx.x & 63;
  if (lane == 0) red[wave] = s;
  __syncthreads();
  if (threadIdx.x == 0) {
    const float tot = red[0] + red[1] + red[2] + red[3];
    const float m = tot / 16777216.0f;      // mean((x_q - x)^2)
    out[OUT_LOSS] = m + 0.25f * m;          // codebook + BETA * commitment
  }
}

// ---------------------------------------------------------------------------
extern "C" void kernel_launch(void* const* d_in, const int* in_sizes, int n_in,
                              void* d_out, int out_size, void* d_ws, size_t ws_size,
                              hipStream_t stream) {
  (void)in_sizes; (void)n_in; (void)out_size; (void)ws_size;
  const float* x = (const float*)d_in[0];
  const float* emb = (const float*)d_in[1];
  float* out = (float*)d_out;
  char* ws = (char*)d_ws;

  // xh/xl (64 MB, exact fit) live in the x_q output region: dead until
  // vq_epilogue overwrites it (after vq_mfma completes on-stream).
  f16* xh = (f16*)out;
  f16* xl = (f16*)((char*)out + 33554432);

  // ws layout: eh[4MB] | el[4MB] | c[256KB] | e2[32KB] | minkey[512KB] | blocksum[64KB]
  f16* eh = (f16*)ws;
  f16* el = (f16*)(ws + 4194304);
  float* c_g = (float*)(ws + 8388608);
  float* e2_g = (float*)(ws + 8650752);
  unsigned long long* minkey = (unsigned long long*)(ws + 8683520);
  float* blocksum = (float*)(ws + 9207808);

  hipMemsetAsync(minkey, 0xFF, (size_t)N_ROWS * 8, stream);  // u64 max for atomicMin

  prep_x<<<N_ROWS / 4, 256, 0, stream>>>(x, xh, xl, c_g);
  prep_e<<<NE / 4, 256, 0, stream>>>(emb, eh, el, e2_g);

  vq_mfma<<<dim3(NE / 128, N_ROWS / 128), 256, 0, stream>>>(
      xh, xl, eh, el, c_g, e2_g, out + OUT_D, minkey);

  vq_epilogue<<<N_ROWS / 4, 256, 0, stream>>>(x, emb, minkey, out, blocksum);
  vq_finalize<<<1, 256, 0, stream>>>(blocksum, out);
}